// Round 11
// baseline (288.572 us; speedup 1.0000x reference)
//
#include <hip/hip_runtime.h>
#include <hip/hip_fp16.h>
#include <math.h>

#define SRLEN   640000
#define NFRAMES 2501
#define FPB     8
#define SPAN    (256*(FPB-1) + 1024)   // 2816
#define MROW    520                    // padded mag row in halfs (513 used)
#define MAXW    48                     // max mel filter width in bins (actual max ~28)

__device__ __forceinline__ int rev6(int x) { return (int)(__brev((unsigned)x) >> 26); }

// ---- packed dual-FP32 helpers (VOP3P) ----
__device__ __forceinline__ float2 pk_add2(float2 a, float2 b) {
    float2 d; asm("v_pk_add_f32 %0, %1, %2" : "=v"(d) : "v"(a), "v"(b)); return d;
}
__device__ __forceinline__ float2 pk_sub2(float2 a, float2 b) {   // a - b
    float2 d; asm("v_pk_fma_f32 %0, %1, -1.0, %2" : "=v"(d) : "v"(b), "v"(a)); return d;
}
__device__ __forceinline__ float2 pk_mul2(float2 a, float2 b) {
    float2 d; asm("v_pk_mul_f32 %0, %1, %2" : "=v"(d) : "v"(a), "v"(b)); return d;
}
__device__ __forceinline__ float2 pk_fma2(float2 a, float2 b, float2 c) {
    float2 d; asm("v_pk_fma_f32 %0, %1, %2, %3" : "=v"(d) : "v"(a), "v"(b), "v"(c)); return d;
}
// complex multiply: d=(dr,di), w=(c,s), ws=(-s,c) -> (dr*c - di*s, dr*s + di*c)
__device__ __forceinline__ float2 cmul2(float2 d, float2 w, float2 ws) {
    float2 t, o;
    asm("v_pk_mul_f32 %0, %1, %2 op_sel:[0,0] op_sel_hi:[0,1]" : "=v"(t) : "v"(d), "v"(w));
    asm("v_pk_fma_f32 %0, %1, %2, %3 op_sel:[1,0,0] op_sel_hi:[1,1,1]" : "=v"(o) : "v"(d), "v"(ws), "v"(t));
    return o;
}

// precomputed per-launch tables
__device__ float4 g_tw4[256];       // (cos, sin, -sin, cos) for exp(-i*pi*j/256)
__device__ float2 g_twu[512];       // exp(-i*pi*k/512)
__device__ int    g_fbs[128];       // first bin per mel (forced even)
__device__ int    g_fbc[128];       // bin count per mel (forced even, zero-padded)
__device__ float  g_fbw[MAXW][128]; // compact weights, transposed for coalescing

// -------- K0: twiddle tables + sparse filterbank compaction (128 blocks) --------
__global__ __launch_bounds__(256)
void pcen_setup_kernel(const float* __restrict__ fb)
{
    const int tid = threadIdx.x;
    const int m   = blockIdx.x;

    if (m == 0) {
        float s, c;
        __sincosf(-3.14159265358979323846f * (float)tid / 256.0f, &s, &c);
        g_tw4[tid] = make_float4(c, s, -s, c);
    }
    if (m == 1) {
        for (int k = tid; k < 512; k += 256) {
            float s, c;
            __sincosf(-3.14159265358979323846f * (float)k / 512.0f, &s, &c);
            g_twu[k] = make_float2(c, s);
        }
    }

    __shared__ int smn[256], smx[256];
    int s = 0x7fffffff, e = -1;
    for (int f = tid; f < 513; f += 256) {
        if (fb[f * 128 + m] != 0.0f) { s = min(s, f); e = max(e, f); }
    }
    smn[tid] = s; smx[tid] = e;
    __syncthreads();
    for (int o = 128; o > 0; o >>= 1) {
        if (tid < o) {
            smn[tid] = min(smn[tid], smn[tid + o]);
            smx[tid] = max(smx[tid], smx[tid + o]);
        }
        __syncthreads();
    }
    int S   = (smx[0] < 0) ? 0 : (smn[0] & ~1);           // force even start
    int cnt = (smx[0] < 0) ? 0 : (smx[0] - S + 1);
    if (cnt > MAXW) cnt = MAXW;
    int cntE = (cnt + 1) & ~1;                             // force even count
    if (tid == 0) { g_fbs[m] = S; g_fbc[m] = cntE; }
    for (int k = tid; k < cntE; k += 256)
        g_fbw[k][m] = (k < cnt) ? fb[(S + k) * 128 + m] : 0.0f;
}

// -------- K1: frames -> windowed rFFT magnitude (fp16) -> mel energies E[b][m][t] --------
// LDS 19.6 KB (span f32 + mags fp16) + VGPR<=64 (packed math) -> 8 blocks/CU target.
__global__ __launch_bounds__(256)
void pcen_spec_kernel(const float* __restrict__ x, const float* __restrict__ win,
                      float* __restrict__ E)
{
    __shared__ float  span[SPAN];          // 11.3 KB
    __shared__ __half mags[FPB][MROW];     // 8.3 KB

    const int tid = threadIdx.x;
    const int t0  = blockIdx.x * FPB;
    const int b   = blockIdx.y;

    // ---- load input span with reflect padding ----
    const float* xb = x + (size_t)b * SRLEN;
    for (int j = tid; j < SPAN; j += 256) {
        int src = t0 * 256 + j - 512;
        src = (src < 0) ? -src : src;
        src = (src >= SRLEN) ? (2 * SRLEN - 2 - src) : src;
        span[j] = xb[src];
    }
    __syncthreads();

    const int lane = tid & 63;
    const int wid  = tid >> 6;
    const int lp   = rev6(lane);
    const int p0lane = rev6((64 - lp) & 63);

    // each wave handles 2 frames, fully in registers
    for (int ff = 0; ff < 2; ++ff) {
        const int fr = wid * 2 + ff;
        float2 zz[8];   // (re, im) packed pairs

        // pack: n = rg*64 + lane ; z[n] = xw[2n] + i*xw[2n+1]
        #pragma unroll
        for (int rg = 0; rg < 8; ++rg) {
            int n = rg * 64 + lane;
            float2 sp = *(const float2*)&span[fr * 256 + 2 * n];
            float2 w  = *(const float2*)&win[2 * n];
            zz[rg] = pk_mul2(sp, w);
        }

        // ---- DIF stage m=256: pairs (r, r+4) ----
        #pragma unroll
        for (int rg = 0; rg < 4; ++rg) {
            const float4 t4 = g_tw4[rg * 64 + lane];
            float2 a = zz[rg], b2 = zz[rg + 4];
            zz[rg] = pk_add2(a, b2);
            zz[rg + 4] = cmul2(pk_sub2(a, b2),
                               make_float2(t4.x, t4.y), make_float2(t4.z, t4.w));
        }
        // ---- stage m=128: pairs (r, r+2) in each half ----
        #pragma unroll
        for (int q = 0; q < 2; ++q) {
            const float4 t4 = g_tw4[(q * 64 + lane) * 2];
            const float2 w2  = make_float2(t4.x, t4.y);
            const float2 ws2 = make_float2(t4.z, t4.w);
            #pragma unroll
            for (int h = 0; h < 2; ++h) {
                int rt = h * 4 + q, rb = rt + 2;
                float2 a = zz[rt], b2 = zz[rb];
                zz[rt] = pk_add2(a, b2);
                zz[rb] = cmul2(pk_sub2(a, b2), w2, ws2);
            }
        }
        // ---- stage m=64: pairs (r, r+1) ----
        {
            const float4 t4 = g_tw4[lane * 4];
            const float2 w2  = make_float2(t4.x, t4.y);
            const float2 ws2 = make_float2(t4.z, t4.w);
            #pragma unroll
            for (int rt = 0; rt < 8; rt += 2) {
                int rb = rt + 1;
                float2 a = zz[rt], b2 = zz[rb];
                zz[rt] = pk_add2(a, b2);
                zz[rb] = cmul2(pk_sub2(a, b2), w2, ws2);
            }
        }
        // ---- 6 cross-lane stages: mask = 32..1 ----
        #pragma unroll
        for (int st = 0; st < 6; ++st) {
            const int mask = 32 >> st;
            const float4 t4 = g_tw4[(lane & (mask - 1)) * (256 / mask)];
            const bool bot = (lane & mask) != 0;
            const float2 w2  = bot ? make_float2(t4.x, t4.y) : make_float2(1.0f, 0.0f);
            const float2 ws2 = bot ? make_float2(t4.z, t4.w) : make_float2(0.0f, 1.0f);
            const float2 sgv = bot ? make_float2(-1.0f, -1.0f) : make_float2(1.0f, 1.0f);
            #pragma unroll
            for (int rg = 0; rg < 8; ++rg) {
                float2 o = zz[rg];
                float2 p = make_float2(__shfl_xor(o.x, mask), __shfl_xor(o.y, mask));
                float2 t = pk_fma2(o, sgv, p);      // top: p+o ; bottom: p-o
                zz[rg] = cmul2(t, w2, ws2);
            }
        }

        // natural Z order: lane lp holds Z[8*lp + q] at reg R3[q]; R3 = {0,4,2,6,1,5,3,7}
        #define WZ(q) zz[(q)==0?0:(q)==1?4:(q)==2?2:(q)==3?6:(q)==4?1:(q)==5?5:(q)==6?3:7]

        float mg[8];
        #define MAG(q, MR, MI) { \
            float2 zv = WZ(q); \
            float mr = (MR), mi = (MI); \
            const float2 tw = g_twu[lp * 8 + (q)]; \
            float xer = 0.5f * (zv.x + mr), xei = 0.5f * (zv.y - mi); \
            float xo  = 0.5f * (zv.y + mi), xoi = 0.5f * (mr - zv.x); \
            float2 v = pk_add2(make_float2(xer, xei), \
                               cmul2(make_float2(xo, xoi), tw, make_float2(-tw.y, tw.x))); \
            mg[q] = sqrtf(v.x * v.x + v.y * v.y); }

        {
            float p0re = __shfl(WZ(0).x, p0lane);
            float p0im = __shfl(WZ(0).y, p0lane);
            MAG(0, p0re, p0im)
        }
        {
            float pr = __shfl_xor(WZ(4).x, 63);
            float pi = __shfl_xor(WZ(4).y, 63);
            MAG(4, pr, pi)
        }
        #pragma unroll
        for (int q = 1; q <= 3; ++q) {
            float prq  = __shfl_xor(WZ(q).x, 63);
            float piq  = __shfl_xor(WZ(q).y, 63);
            float prq8 = __shfl_xor(WZ(8 - q).x, 63);
            float piq8 = __shfl_xor(WZ(8 - q).y, 63);
            MAG(q, prq8, piq8)
            MAG(8 - q, prq, piq)
        }
        #undef MAG
        #undef WZ

        union { __half2 h2[4]; float4 f4; } pk;
        pk.h2[0] = __floats2half2_rn(mg[0], mg[1]);
        pk.h2[1] = __floats2half2_rn(mg[2], mg[3]);
        pk.h2[2] = __floats2half2_rn(mg[4], mg[5]);
        pk.h2[3] = __floats2half2_rn(mg[6], mg[7]);
        *(float4*)&mags[fr][lp * 8] = pk.f4;
        if (lane == 0) {
            mags[fr][512] = __float2half(fabsf(zz[0].x - zz[0].y));  // Nyquist
            mags[fr][513] = __float2half(0.0f);                      // pad for half2 reads
        }
    }
    __syncthreads();

    // ---- sparse mel projection via half2: m = tid&127, fg = tid>>7 covers 4 frames ----
    const int m  = tid & 127;
    const int fg = tid >> 7;
    const int s0 = g_fbs[m];   // even
    const int cn = g_fbc[m];   // even
    float acc[4] = {0, 0, 0, 0};
    for (int k = 0; k < cn; k += 2) {
        const float w0 = g_fbw[k][m];
        const float w1 = g_fbw[k + 1][m];
        const int f = s0 + k;
        #pragma unroll
        for (int j = 0; j < 4; ++j) {
            const __half2 h = *(const __half2*)&mags[fg * 4 + j][f];
            acc[j] = fmaf(w0, __half2float(h.x), fmaf(w1, __half2float(h.y), acc[j]));
        }
    }
    #pragma unroll
    for (int j = 0; j < 4; ++j) {
        int t = t0 + fg * 4 + j;
        if (t < NFRAMES)
            E[((size_t)(b * 128 + m)) * NFRAMES + t] = acc[j];
    }
}

// -------- K2: per-(b,m) IIR scan + PCEN nonlinearity, in place on E --------
__global__ __launch_bounds__(256)
void pcen_scan_kernel(float* __restrict__ E, const float* __restrict__ alpha,
                      const float* __restrict__ delta, const float* __restrict__ rr)
{
    __shared__ float sA[256], sB[256];
    __shared__ float row[2560];
    const int tid = threadIdx.x;
    const int bm  = blockIdx.x;
    const int m   = bm & 127;
    const size_t base = (size_t)bm * NFRAMES;

    const float al = alpha[m], de = delta[m], rp = rr[m];
    const float dpr = __powf(de, rp);

    // coalesced row load into LDS
    for (int t = tid; t < NFRAMES; t += 256) row[t] = E[base + t];
    if (tid < 2560 - NFRAMES) row[NFRAMES + tid] = 0.0f;
    __syncthreads();

    float e[10];
    #pragma unroll
    for (int j = 0; j < 10; ++j) e[j] = row[tid * 10 + j];

    // local fold of (a,b) pairs; identity (1,0) for padding
    float A = 1.0f, B = 0.0f;
    #pragma unroll
    for (int j = 0; j < 10; ++j) {
        int t = tid * 10 + j;
        bool v = t < NFRAMES;
        float a  = (t == 0) ? 1.0f : (v ? 0.96f : 1.0f);
        float bv = (t == 0) ? e[0] : (v ? 0.04f * e[j] : 0.0f);
        A *= a;
        B = a * B + bv;
    }
    sA[tid] = A; sB[tid] = B;
    __syncthreads();

    // Hillis-Steele inclusive scan over thread chunks
    for (int off = 1; off < 256; off <<= 1) {
        float a2 = sA[tid], b2 = sB[tid];
        float a1 = 1.0f, b1 = 0.0f;
        if (tid >= off) { a1 = sA[tid - off]; b1 = sB[tid - off]; }
        __syncthreads();
        sA[tid] = a1 * a2;
        sB[tid] = a2 * b1 + b2;
        __syncthreads();
    }
    float M = (tid > 0) ? sB[tid - 1] : 0.0f;   // carry: M before this chunk

    #pragma unroll
    for (int j = 0; j < 10; ++j) {
        int t = tid * 10 + j;
        bool v = t < NFRAMES;
        float a  = (t == 0) ? 1.0f : (v ? 0.96f : 1.0f);
        float bv = (t == 0) ? e[0] : (v ? 0.04f * e[j] : 0.0f);
        M = a * M + bv;
        if (v) {
            float inv = __powf(M + 1e-6f, -al);            // smooth^-1
            float val = fmaf(e[j], inv, de);
            row[t] = __powf(val, rp) - dpr;
        }
    }
    __syncthreads();

    // coalesced store
    for (int t = tid; t < NFRAMES; t += 256) E[base + t] = row[t];
}

extern "C" void kernel_launch(void* const* d_in, const int* in_sizes, int n_in,
                              void* d_out, int out_size, void* d_ws, size_t ws_size,
                              hipStream_t stream)
{
    const float* x     = (const float*)d_in[0];
    const float* alpha = (const float*)d_in[1];
    const float* delta = (const float*)d_in[2];
    const float* r     = (const float*)d_in[3];
    const float* fb    = (const float*)d_in[4];
    const float* win   = (const float*)d_in[5];
    float* out = (float*)d_out;

    pcen_setup_kernel<<<128, 256, 0, stream>>>(fb);
    dim3 g1((NFRAMES + FPB - 1) / FPB, 32);   // 313 x 32
    pcen_spec_kernel<<<g1, 256, 0, stream>>>(x, win, out);
    pcen_scan_kernel<<<32 * 128, 256, 0, stream>>>(out, alpha, delta, r);
}

// Round 12
// 256.584 us; speedup vs baseline: 1.1247x; 1.1247x over previous
//
#include <hip/hip_runtime.h>
#include <math.h>

#define SRLEN   640000
#define NFRAMES 2501
#define FPB     16
#define SPAN    (256*(FPB-1) + 1024)   // 4864
#define MROW    520                    // padded mag row in f32 (513 used, 514 padded)
#define MAXW    48                     // max mel filter width in bins (actual max ~28)

__device__ __forceinline__ int rev6(int x) { return (int)(__brev((unsigned)x) >> 26); }

// precomputed per-launch tables
__device__ float2 g_tw512[256];     // exp(-i*pi*j/256)
__device__ float2 g_twu[512];       // exp(-i*pi*k/512)
__device__ int    g_fbs[128];       // first bin per mel (forced even)
__device__ int    g_fbc[128];       // bin count per mel (forced even, zero-padded)
__device__ float  g_fbw[MAXW][128]; // compact weights, transposed for coalescing

// -------- K0: twiddle tables + sparse filterbank compaction (128 blocks) --------
__global__ __launch_bounds__(256)
void pcen_setup_kernel(const float* __restrict__ fb)
{
    const int tid = threadIdx.x;
    const int m   = blockIdx.x;

    if (m == 0) {
        float s, c;
        __sincosf(-3.14159265358979323846f * (float)tid / 256.0f, &s, &c);
        g_tw512[tid] = make_float2(c, s);
    }
    if (m == 1) {
        for (int k = tid; k < 512; k += 256) {
            float s, c;
            __sincosf(-3.14159265358979323846f * (float)k / 512.0f, &s, &c);
            g_twu[k] = make_float2(c, s);
        }
    }

    __shared__ int smn[256], smx[256];
    int s = 0x7fffffff, e = -1;
    for (int f = tid; f < 513; f += 256) {
        if (fb[f * 128 + m] != 0.0f) { s = min(s, f); e = max(e, f); }
    }
    smn[tid] = s; smx[tid] = e;
    __syncthreads();
    for (int o = 128; o > 0; o >>= 1) {
        if (tid < o) {
            smn[tid] = min(smn[tid], smn[tid + o]);
            smx[tid] = max(smx[tid], smx[tid + o]);
        }
        __syncthreads();
    }
    int S   = (smx[0] < 0) ? 0 : (smn[0] & ~1);           // force even start
    int cnt = (smx[0] < 0) ? 0 : (smx[0] - S + 1);
    if (cnt > MAXW) cnt = MAXW;
    int cntE = (cnt + 1) & ~1;                             // force even count
    if (tid == 0) { g_fbs[m] = S; g_fbc[m] = cntE; }
    for (int k = tid; k < cntE; k += 256)
        g_fbw[k][m] = (k < cnt) ? fb[(S + k) * 128 + m] : 0.0f;
}

// -------- K1: frames -> windowed rFFT magnitude (f32) -> mel energies E[b][m][t] --------
// R3-proven config: FPB16, all-f32, scalar math, rolled 4-frame wave loop. LDS 52.7KB.
__global__ __launch_bounds__(256)
void pcen_spec_kernel(const float* __restrict__ x, const float* __restrict__ win,
                      float* __restrict__ E)
{
    __shared__ float span[SPAN];        // 19.0 KB
    __shared__ float mags[FPB][MROW];   // 33.3 KB

    const int tid = threadIdx.x;
    const int t0  = blockIdx.x * FPB;
    const int b   = blockIdx.y;

    // ---- load input span with reflect padding ----
    const float* xb = x + (size_t)b * SRLEN;
    for (int j = tid; j < SPAN; j += 256) {
        int src = t0 * 256 + j - 512;
        src = (src < 0) ? -src : src;
        src = (src >= SRLEN) ? (2 * SRLEN - 2 - src) : src;
        span[j] = xb[src];
    }
    __syncthreads();

    const int lane = tid & 63;
    const int wid  = tid >> 6;
    const int lp   = rev6(lane);
    const int p0lane = rev6((64 - lp) & 63);

    // each wave handles 4 frames, fully in registers (rolled loop, small I-footprint)
    for (int ff = 0; ff < 4; ++ff) {
        const int fr = wid * 4 + ff;
        float zre[8], zim[8];

        // pack: n = rg*64 + lane ; z[n] = xw[2n] + i*xw[2n+1]
        #pragma unroll
        for (int rg = 0; rg < 8; ++rg) {
            int n = rg * 64 + lane;
            float2 sp = *(const float2*)&span[fr * 256 + 2 * n];
            float2 w  = *(const float2*)&win[2 * n];
            zre[rg] = sp.x * w.x;
            zim[rg] = sp.y * w.y;
        }

        // ---- DIF stage m=256: pairs (r, r+4) ----
        #pragma unroll
        for (int rg = 0; rg < 4; ++rg) {
            const float2 tw = g_tw512[rg * 64 + lane];
            float ar = zre[rg], ai = zim[rg], br = zre[rg + 4], bi = zim[rg + 4];
            zre[rg] = ar + br; zim[rg] = ai + bi;
            float dr = ar - br, di = ai - bi;
            zre[rg + 4] = dr * tw.x - di * tw.y;
            zim[rg + 4] = dr * tw.y + di * tw.x;
        }
        // ---- stage m=128: pairs (r, r+2) in each half ----
        #pragma unroll
        for (int h = 0; h < 2; ++h) {
            #pragma unroll
            for (int q = 0; q < 2; ++q) {
                int rt = h * 4 + q, rb = rt + 2;
                const float2 tw = g_tw512[(q * 64 + lane) * 2];
                float ar = zre[rt], ai = zim[rt], br = zre[rb], bi = zim[rb];
                zre[rt] = ar + br; zim[rt] = ai + bi;
                float dr = ar - br, di = ai - bi;
                zre[rb] = dr * tw.x - di * tw.y;
                zim[rb] = dr * tw.y + di * tw.x;
            }
        }
        // ---- stage m=64: pairs (r, r+1) ----
        {
            const float2 tw = g_tw512[lane * 4];
            #pragma unroll
            for (int rt = 0; rt < 8; rt += 2) {
                int rb = rt + 1;
                float ar = zre[rt], ai = zim[rt], br = zre[rb], bi = zim[rb];
                zre[rt] = ar + br; zim[rt] = ai + bi;
                float dr = ar - br, di = ai - bi;
                zre[rb] = dr * tw.x - di * tw.y;
                zim[rb] = dr * tw.y + di * tw.x;
            }
        }
        // ---- 6 cross-lane stages: mask = 32..1 ----
        #pragma unroll
        for (int st = 0; st < 6; ++st) {
            const int mask = 32 >> st;
            const float2 tw = g_tw512[(lane & (mask - 1)) * (256 / mask)];
            const bool bot = (lane & mask) != 0;
            const float cw = bot ? tw.x : 1.0f;
            const float sw = bot ? tw.y : 0.0f;
            const float sg = bot ? -1.0f : 1.0f;
            #pragma unroll
            for (int rg = 0; rg < 8; ++rg) {
                float orr = zre[rg], oii = zim[rg];
                float prr = __shfl_xor(orr, mask);
                float pri = __shfl_xor(oii, mask);
                float tr = prr + sg * orr;   // top: a+b ; bottom: a-b
                float ti = pri + sg * oii;
                zre[rg] = tr * cw - ti * sw;
                zim[rg] = tr * sw + ti * cw;
            }
        }

        // natural Z order: lane lp holds Z[8*lp + q] at reg R3[q]; R3 = {0,4,2,6,1,5,3,7}
        #define WRE(q) zre[(q)==0?0:(q)==1?4:(q)==2?2:(q)==3?6:(q)==4?1:(q)==5?5:(q)==6?3:7]
        #define WIM(q) zim[(q)==0?0:(q)==1?4:(q)==2?2:(q)==3?6:(q)==4?1:(q)==5?5:(q)==6?3:7]

        float mg[8];
        #define MAG(q, MR, MI) { \
            float zr = WRE(q), zi = WIM(q); \
            float mr = (MR), mi = (MI); \
            const float2 tw = g_twu[lp * 8 + (q)]; \
            float xer = 0.5f * (zr + mr), xei = 0.5f * (zi - mi); \
            float xo  = 0.5f * (zi + mi), xoi = 0.5f * (mr - zr); \
            float xr = xer + tw.x * xo - tw.y * xoi; \
            float xi = xei + tw.x * xoi + tw.y * xo; \
            mg[q] = sqrtf(xr * xr + xi * xi); }

        {
            float p0re = __shfl(WRE(0), p0lane);
            float p0im = __shfl(WIM(0), p0lane);
            MAG(0, p0re, p0im)
        }
        {
            float pr = __shfl_xor(WRE(4), 63);
            float pi = __shfl_xor(WIM(4), 63);
            MAG(4, pr, pi)
        }
        #pragma unroll
        for (int q = 1; q <= 3; ++q) {
            float prq  = __shfl_xor(WRE(q), 63);
            float piq  = __shfl_xor(WIM(q), 63);
            float prq8 = __shfl_xor(WRE(8 - q), 63);
            float piq8 = __shfl_xor(WIM(8 - q), 63);
            MAG(q, prq8, piq8)
            MAG(8 - q, prq, piq)
        }
        #undef MAG
        #undef WRE
        #undef WIM

        *(float4*)&mags[fr][lp * 8]     = make_float4(mg[0], mg[1], mg[2], mg[3]);
        *(float4*)&mags[fr][lp * 8 + 4] = make_float4(mg[4], mg[5], mg[6], mg[7]);
        if (lane == 0) {
            mags[fr][512] = fabsf(zre[0] - zim[0]);  // Nyquist
            mags[fr][513] = 0.0f;                    // pad for float2 mel reads
        }
    }
    __syncthreads();

    // ---- sparse mel projection via float2: m = tid&127, fg = tid>>7 covers 8 frames ----
    const int m  = tid & 127;
    const int fg = tid >> 7;
    const int s0 = g_fbs[m];   // even
    const int cn = g_fbc[m];   // even
    float acc[8] = {0, 0, 0, 0, 0, 0, 0, 0};
    for (int k = 0; k < cn; k += 2) {
        const float w0 = g_fbw[k][m];
        const float w1 = g_fbw[k + 1][m];
        const int f = s0 + k;
        #pragma unroll
        for (int j = 0; j < 8; ++j) {
            const float2 v = *(const float2*)&mags[fg * 8 + j][f];
            acc[j] = fmaf(w0, v.x, fmaf(w1, v.y, acc[j]));
        }
    }
    #pragma unroll
    for (int j = 0; j < 8; ++j) {
        int t = t0 + fg * 8 + j;
        if (t < NFRAMES)
            E[((size_t)(b * 128 + m)) * NFRAMES + t] = acc[j];
    }
}

// -------- K2: per-(b,m) IIR scan + PCEN nonlinearity, in place on E --------
__global__ __launch_bounds__(256)
void pcen_scan_kernel(float* __restrict__ E, const float* __restrict__ alpha,
                      const float* __restrict__ delta, const float* __restrict__ rr)
{
    __shared__ float sA[256], sB[256];
    __shared__ float row[2560];
    const int tid = threadIdx.x;
    const int bm  = blockIdx.x;
    const int m   = bm & 127;
    const size_t base = (size_t)bm * NFRAMES;

    const float al = alpha[m], de = delta[m], rp = rr[m];
    const float dpr = __powf(de, rp);

    // coalesced row load into LDS
    for (int t = tid; t < NFRAMES; t += 256) row[t] = E[base + t];
    if (tid < 2560 - NFRAMES) row[NFRAMES + tid] = 0.0f;
    __syncthreads();

    float e[10];
    #pragma unroll
    for (int j = 0; j < 10; ++j) e[j] = row[tid * 10 + j];

    // local fold of (a,b) pairs; identity (1,0) for padding
    float A = 1.0f, B = 0.0f;
    #pragma unroll
    for (int j = 0; j < 10; ++j) {
        int t = tid * 10 + j;
        bool v = t < NFRAMES;
        float a  = (t == 0) ? 1.0f : (v ? 0.96f : 1.0f);
        float bv = (t == 0) ? e[0] : (v ? 0.04f * e[j] : 0.0f);
        A *= a;
        B = a * B + bv;
    }
    sA[tid] = A; sB[tid] = B;
    __syncthreads();

    // Hillis-Steele inclusive scan over thread chunks
    for (int off = 1; off < 256; off <<= 1) {
        float a2 = sA[tid], b2 = sB[tid];
        float a1 = 1.0f, b1 = 0.0f;
        if (tid >= off) { a1 = sA[tid - off]; b1 = sB[tid - off]; }
        __syncthreads();
        sA[tid] = a1 * a2;
        sB[tid] = a2 * b1 + b2;
        __syncthreads();
    }
    float M = (tid > 0) ? sB[tid - 1] : 0.0f;   // carry: M before this chunk

    #pragma unroll
    for (int j = 0; j < 10; ++j) {
        int t = tid * 10 + j;
        bool v = t < NFRAMES;
        float a  = (t == 0) ? 1.0f : (v ? 0.96f : 1.0f);
        float bv = (t == 0) ? e[0] : (v ? 0.04f * e[j] : 0.0f);
        M = a * M + bv;
        if (v) {
            float inv = __powf(M + 1e-6f, -al);            // smooth^-1
            float val = fmaf(e[j], inv, de);
            row[t] = __powf(val, rp) - dpr;
        }
    }
    __syncthreads();

    // coalesced store
    for (int t = tid; t < NFRAMES; t += 256) E[base + t] = row[t];
}

extern "C" void kernel_launch(void* const* d_in, const int* in_sizes, int n_in,
                              void* d_out, int out_size, void* d_ws, size_t ws_size,
                              hipStream_t stream)
{
    const float* x     = (const float*)d_in[0];
    const float* alpha = (const float*)d_in[1];
    const float* delta = (const float*)d_in[2];
    const float* r     = (const float*)d_in[3];
    const float* fb    = (const float*)d_in[4];
    const float* win   = (const float*)d_in[5];
    float* out = (float*)d_out;

    pcen_setup_kernel<<<128, 256, 0, stream>>>(fb);
    dim3 g1((NFRAMES + FPB - 1) / FPB, 32);   // 157 x 32
    pcen_spec_kernel<<<g1, 256, 0, stream>>>(x, win, out);
    pcen_scan_kernel<<<32 * 128, 256, 0, stream>>>(out, alpha, delta, r);
}

// Round 13
// 241.324 us; speedup vs baseline: 1.1958x; 1.0632x over previous
//
#include <hip/hip_runtime.h>
#include <math.h>

#define SRLEN   640000
#define NFRAMES 2501
#define FPB     16
#define SPAN    (256*(FPB-1) + 1024)   // 4864
#define MROW    520                    // padded mag row in f32 (513 used, 514 padded)
#define MAXW    48                     // max mel filter width in bins (actual max ~28)

__device__ __forceinline__ int rev6(int x) { return (int)(__brev((unsigned)x) >> 26); }

// DPP lane-permute on the VALU pipe (not DS). ctrl: quad_perm / row mirrors.
// 0xB1 = quad_perm[1,0,3,2] (xor1)   0x4E = quad_perm[2,3,0,1] (xor2)
// 0x1B = quad_perm[3,2,1,0] (xor3)   0x140 = row_mirror (xor15)  0x141 = half_mirror (xor7)
#define DPPF(x, ctrl) __int_as_float(__builtin_amdgcn_update_dpp(0, __float_as_int(x), (ctrl), 0xF, 0xF, false))

// precomputed per-launch tables
__device__ float2 g_tw512[256];     // exp(-i*pi*j/256)
__device__ float2 g_twu[512];       // exp(-i*pi*k/512)
__device__ int    g_fbs[128];       // first bin per mel (forced even)
__device__ int    g_fbc[128];       // bin count per mel (forced even, zero-padded)
__device__ float  g_fbw[MAXW][128]; // compact weights, transposed for coalescing

// -------- K0: twiddle tables + sparse filterbank compaction (128 blocks) --------
__global__ __launch_bounds__(256)
void pcen_setup_kernel(const float* __restrict__ fb)
{
    const int tid = threadIdx.x;
    const int m   = blockIdx.x;

    if (m == 0) {
        float s, c;
        __sincosf(-3.14159265358979323846f * (float)tid / 256.0f, &s, &c);
        g_tw512[tid] = make_float2(c, s);
    }
    if (m == 1) {
        for (int k = tid; k < 512; k += 256) {
            float s, c;
            __sincosf(-3.14159265358979323846f * (float)k / 512.0f, &s, &c);
            g_twu[k] = make_float2(c, s);
        }
    }

    __shared__ int smn[256], smx[256];
    int s = 0x7fffffff, e = -1;
    for (int f = tid; f < 513; f += 256) {
        if (fb[f * 128 + m] != 0.0f) { s = min(s, f); e = max(e, f); }
    }
    smn[tid] = s; smx[tid] = e;
    __syncthreads();
    for (int o = 128; o > 0; o >>= 1) {
        if (tid < o) {
            smn[tid] = min(smn[tid], smn[tid + o]);
            smx[tid] = max(smx[tid], smx[tid + o]);
        }
        __syncthreads();
    }
    int S   = (smx[0] < 0) ? 0 : (smn[0] & ~1);           // force even start
    int cnt = (smx[0] < 0) ? 0 : (smx[0] - S + 1);
    if (cnt > MAXW) cnt = MAXW;
    int cntE = (cnt + 1) & ~1;                             // force even count
    if (tid == 0) { g_fbs[m] = S; g_fbc[m] = cntE; }
    for (int k = tid; k < cntE; k += 256)
        g_fbw[k][m] = (k < cnt) ? fb[(S + k) * 128 + m] : 0.0f;
}

// -------- K1: frames -> windowed rFFT magnitude (f32) -> mel energies E[b][m][t] --------
// R12 structure; cross-lane FFT stages 8/4/2/1 moved from DS (ds_bpermute) to VALU (DPP).
__global__ __launch_bounds__(256)
void pcen_spec_kernel(const float* __restrict__ x, const float* __restrict__ win,
                      float* __restrict__ E)
{
    __shared__ float span[SPAN];        // 19.0 KB
    __shared__ float mags[FPB][MROW];   // 33.3 KB

    const int tid = threadIdx.x;
    const int t0  = blockIdx.x * FPB;
    const int b   = blockIdx.y;

    // ---- load input span with reflect padding ----
    const float* xb = x + (size_t)b * SRLEN;
    for (int j = tid; j < SPAN; j += 256) {
        int src = t0 * 256 + j - 512;
        src = (src < 0) ? -src : src;
        src = (src >= SRLEN) ? (2 * SRLEN - 2 - src) : src;
        span[j] = xb[src];
    }
    __syncthreads();

    const int lane = tid & 63;
    const int wid  = tid >> 6;
    const int lp   = rev6(lane);
    const int p0lane = rev6((64 - lp) & 63);

    // each wave handles 4 frames, fully in registers
    for (int ff = 0; ff < 4; ++ff) {
        const int fr = wid * 4 + ff;
        float zre[8], zim[8];

        // pack: n = rg*64 + lane ; z[n] = xw[2n] + i*xw[2n+1]
        #pragma unroll
        for (int rg = 0; rg < 8; ++rg) {
            int n = rg * 64 + lane;
            float2 sp = *(const float2*)&span[fr * 256 + 2 * n];
            float2 w  = *(const float2*)&win[2 * n];
            zre[rg] = sp.x * w.x;
            zim[rg] = sp.y * w.y;
        }

        // ---- DIF stage m=256: pairs (r, r+4) ----
        #pragma unroll
        for (int rg = 0; rg < 4; ++rg) {
            const float2 tw = g_tw512[rg * 64 + lane];
            float ar = zre[rg], ai = zim[rg], br = zre[rg + 4], bi = zim[rg + 4];
            zre[rg] = ar + br; zim[rg] = ai + bi;
            float dr = ar - br, di = ai - bi;
            zre[rg + 4] = dr * tw.x - di * tw.y;
            zim[rg + 4] = dr * tw.y + di * tw.x;
        }
        // ---- stage m=128: pairs (r, r+2) in each half ----
        #pragma unroll
        for (int h = 0; h < 2; ++h) {
            #pragma unroll
            for (int q = 0; q < 2; ++q) {
                int rt = h * 4 + q, rb = rt + 2;
                const float2 tw = g_tw512[(q * 64 + lane) * 2];
                float ar = zre[rt], ai = zim[rt], br = zre[rb], bi = zim[rb];
                zre[rt] = ar + br; zim[rt] = ai + bi;
                float dr = ar - br, di = ai - bi;
                zre[rb] = dr * tw.x - di * tw.y;
                zim[rb] = dr * tw.y + di * tw.x;
            }
        }
        // ---- stage m=64: pairs (r, r+1) ----
        {
            const float2 tw = g_tw512[lane * 4];
            #pragma unroll
            for (int rt = 0; rt < 8; rt += 2) {
                int rb = rt + 1;
                float ar = zre[rt], ai = zim[rt], br = zre[rb], bi = zim[rb];
                zre[rt] = ar + br; zim[rt] = ai + bi;
                float dr = ar - br, di = ai - bi;
                zre[rb] = dr * tw.x - di * tw.y;
                zim[rb] = dr * tw.y + di * tw.x;
            }
        }

        // ---- 6 cross-lane stages. Partner via DS shuffle (32,16) or DPP (8,4,2,1). ----
        #define BFLY(MASK, PRE, PIM) { \
            const float2 tw = g_tw512[(lane & ((MASK) - 1)) * (256 / (MASK))]; \
            const bool bot = (lane & (MASK)) != 0; \
            const float cw = bot ? tw.x : 1.0f; \
            const float sw = bot ? tw.y : 0.0f; \
            const float sg = bot ? -1.0f : 1.0f; \
            _Pragma("unroll") \
            for (int rg = 0; rg < 8; ++rg) { \
                float orr = zre[rg], oii = zim[rg]; \
                float prr = (PRE); \
                float pri = (PIM); \
                float tr = fmaf(sg, orr, prr); \
                float ti = fmaf(sg, oii, pri); \
                zre[rg] = tr * cw - ti * sw; \
                zim[rg] = tr * sw + ti * cw; \
            } }

        BFLY(32, __shfl_xor(orr, 32), __shfl_xor(oii, 32))
        BFLY(16, __shfl_xor(orr, 16), __shfl_xor(oii, 16))
        BFLY(8,  DPPF(DPPF(orr, 0x140), 0x141), DPPF(DPPF(oii, 0x140), 0x141))  // xor8 = 15^7
        BFLY(4,  DPPF(DPPF(orr, 0x141), 0x1B),  DPPF(DPPF(oii, 0x141), 0x1B))   // xor4 = 7^3
        BFLY(2,  DPPF(orr, 0x4E),               DPPF(oii, 0x4E))                // xor2
        BFLY(1,  DPPF(orr, 0xB1),               DPPF(oii, 0xB1))                // xor1
        #undef BFLY

        // natural Z order: lane lp holds Z[8*lp + q] at reg R3[q]; R3 = {0,4,2,6,1,5,3,7}
        #define WRE(q) zre[(q)==0?0:(q)==1?4:(q)==2?2:(q)==3?6:(q)==4?1:(q)==5?5:(q)==6?3:7]
        #define WIM(q) zim[(q)==0?0:(q)==1?4:(q)==2?2:(q)==3?6:(q)==4?1:(q)==5?5:(q)==6?3:7]

        float mg[8];
        #define MAG(q, MR, MI) { \
            float zr = WRE(q), zi = WIM(q); \
            float mr = (MR), mi = (MI); \
            const float2 tw = g_twu[lp * 8 + (q)]; \
            float xer = 0.5f * (zr + mr), xei = 0.5f * (zi - mi); \
            float xo  = 0.5f * (zi + mi), xoi = 0.5f * (mr - zr); \
            float xr = xer + tw.x * xo - tw.y * xoi; \
            float xi = xei + tw.x * xoi + tw.y * xo; \
            mg[q] = sqrtf(xr * xr + xi * xi); }

        {
            float p0re = __shfl(WRE(0), p0lane);
            float p0im = __shfl(WIM(0), p0lane);
            MAG(0, p0re, p0im)
        }
        {
            float pr = __shfl_xor(WRE(4), 63);
            float pi = __shfl_xor(WIM(4), 63);
            MAG(4, pr, pi)
        }
        #pragma unroll
        for (int q = 1; q <= 3; ++q) {
            float prq  = __shfl_xor(WRE(q), 63);
            float piq  = __shfl_xor(WIM(q), 63);
            float prq8 = __shfl_xor(WRE(8 - q), 63);
            float piq8 = __shfl_xor(WIM(8 - q), 63);
            MAG(q, prq8, piq8)
            MAG(8 - q, prq, piq)
        }
        #undef MAG
        #undef WRE
        #undef WIM

        *(float4*)&mags[fr][lp * 8]     = make_float4(mg[0], mg[1], mg[2], mg[3]);
        *(float4*)&mags[fr][lp * 8 + 4] = make_float4(mg[4], mg[5], mg[6], mg[7]);
        if (lane == 0) {
            mags[fr][512] = fabsf(zre[0] - zim[0]);  // Nyquist
            mags[fr][513] = 0.0f;                    // pad for float2 mel reads
        }
    }
    __syncthreads();

    // ---- sparse mel projection via float2: m = tid&127, fg = tid>>7 covers 8 frames ----
    const int m  = tid & 127;
    const int fg = tid >> 7;
    const int s0 = g_fbs[m];   // even
    const int cn = g_fbc[m];   // even
    float acc[8] = {0, 0, 0, 0, 0, 0, 0, 0};
    for (int k = 0; k < cn; k += 2) {
        const float w0 = g_fbw[k][m];
        const float w1 = g_fbw[k + 1][m];
        const int f = s0 + k;
        #pragma unroll
        for (int j = 0; j < 8; ++j) {
            const float2 v = *(const float2*)&mags[fg * 8 + j][f];
            acc[j] = fmaf(w0, v.x, fmaf(w1, v.y, acc[j]));
        }
    }
    #pragma unroll
    for (int j = 0; j < 8; ++j) {
        int t = t0 + fg * 8 + j;
        if (t < NFRAMES)
            E[((size_t)(b * 128 + m)) * NFRAMES + t] = acc[j];
    }
}

// -------- K2: per-(b,m) IIR scan + PCEN nonlinearity, in place on E --------
__global__ __launch_bounds__(256)
void pcen_scan_kernel(float* __restrict__ E, const float* __restrict__ alpha,
                      const float* __restrict__ delta, const float* __restrict__ rr)
{
    __shared__ float sA[256], sB[256];
    __shared__ float row[2560];
    const int tid = threadIdx.x;
    const int bm  = blockIdx.x;
    const int m   = bm & 127;
    const size_t base = (size_t)bm * NFRAMES;

    const float al = alpha[m], de = delta[m], rp = rr[m];
    const float dpr = __powf(de, rp);

    // coalesced row load into LDS
    for (int t = tid; t < NFRAMES; t += 256) row[t] = E[base + t];
    if (tid < 2560 - NFRAMES) row[NFRAMES + tid] = 0.0f;
    __syncthreads();

    float e[10];
    #pragma unroll
    for (int j = 0; j < 10; ++j) e[j] = row[tid * 10 + j];

    // local fold of (a,b) pairs; identity (1,0) for padding
    float A = 1.0f, B = 0.0f;
    #pragma unroll
    for (int j = 0; j < 10; ++j) {
        int t = tid * 10 + j;
        bool v = t < NFRAMES;
        float a  = (t == 0) ? 1.0f : (v ? 0.96f : 1.0f);
        float bv = (t == 0) ? e[0] : (v ? 0.04f * e[j] : 0.0f);
        A *= a;
        B = a * B + bv;
    }
    sA[tid] = A; sB[tid] = B;
    __syncthreads();

    // Hillis-Steele inclusive scan over thread chunks
    for (int off = 1; off < 256; off <<= 1) {
        float a2 = sA[tid], b2 = sB[tid];
        float a1 = 1.0f, b1 = 0.0f;
        if (tid >= off) { a1 = sA[tid - off]; b1 = sB[tid - off]; }
        __syncthreads();
        sA[tid] = a1 * a2;
        sB[tid] = a2 * b1 + b2;
        __syncthreads();
    }
    float M = (tid > 0) ? sB[tid - 1] : 0.0f;   // carry: M before this chunk

    #pragma unroll
    for (int j = 0; j < 10; ++j) {
        int t = tid * 10 + j;
        bool v = t < NFRAMES;
        float a  = (t == 0) ? 1.0f : (v ? 0.96f : 1.0f);
        float bv = (t == 0) ? e[0] : (v ? 0.04f * e[j] : 0.0f);
        M = a * M + bv;
        if (v) {
            float inv = __powf(M + 1e-6f, -al);            // smooth^-1
            float val = fmaf(e[j], inv, de);
            row[t] = __powf(val, rp) - dpr;
        }
    }
    __syncthreads();

    // coalesced store
    for (int t = tid; t < NFRAMES; t += 256) E[base + t] = row[t];
}

extern "C" void kernel_launch(void* const* d_in, const int* in_sizes, int n_in,
                              void* d_out, int out_size, void* d_ws, size_t ws_size,
                              hipStream_t stream)
{
    const float* x     = (const float*)d_in[0];
    const float* alpha = (const float*)d_in[1];
    const float* delta = (const float*)d_in[2];
    const float* r     = (const float*)d_in[3];
    const float* fb    = (const float*)d_in[4];
    const float* win   = (const float*)d_in[5];
    float* out = (float*)d_out;

    pcen_setup_kernel<<<128, 256, 0, stream>>>(fb);
    dim3 g1((NFRAMES + FPB - 1) / FPB, 32);   // 157 x 32
    pcen_spec_kernel<<<g1, 256, 0, stream>>>(x, win, out);
    pcen_scan_kernel<<<32 * 128, 256, 0, stream>>>(out, alpha, delta, r);
}

// Round 14
// 201.149 us; speedup vs baseline: 1.4346x; 1.1997x over previous
//
#include <hip/hip_runtime.h>
#include <math.h>

#define SRLEN   640000
#define NFRAMES 2501
#define FPB     16
#define SPAN    (256*(FPB-1) + 1024)   // 4864
#define MROW    520                    // padded mag row in f32 (513 used, 514 padded)
#define MAXW    48                     // max mel filter width in bins (actual max ~28)

__device__ __forceinline__ int rev6(int x) { return (int)(__brev((unsigned)x) >> 26); }

// DPP lane-permute on the VALU pipe (not DS). ctrl: quad_perm / row mirrors.
// 0xB1 = quad_perm[1,0,3,2] (xor1)   0x4E = quad_perm[2,3,0,1] (xor2)
// 0x1B = quad_perm[3,2,1,0] (xor3)   0x140 = row_mirror (xor15)  0x141 = half_mirror (xor7)
#define DPPF(x, ctrl) __int_as_float(__builtin_amdgcn_update_dpp(0, __float_as_int(x), (ctrl), 0xF, 0xF, false))

// precomputed per-launch tables
__device__ float2 g_tw512[256];     // exp(-i*pi*j/256)
__device__ float2 g_twu[512];       // exp(-i*pi*k/512)
__device__ int    g_fbs[128];       // first bin per mel (forced even)
__device__ int    g_fbc[128];       // bin count per mel (forced even, zero-padded)
__device__ float  g_fbw[MAXW][128]; // compact weights, transposed for coalescing

// -------- K0: twiddle tables + sparse filterbank compaction (128 blocks) --------
__global__ __launch_bounds__(256)
void pcen_setup_kernel(const float* __restrict__ fb)
{
    const int tid = threadIdx.x;
    const int m   = blockIdx.x;

    if (m == 0) {
        float s, c;
        __sincosf(-3.14159265358979323846f * (float)tid / 256.0f, &s, &c);
        g_tw512[tid] = make_float2(c, s);
    }
    if (m == 1) {
        for (int k = tid; k < 512; k += 256) {
            float s, c;
            __sincosf(-3.14159265358979323846f * (float)k / 512.0f, &s, &c);
            g_twu[k] = make_float2(c, s);
        }
    }

    __shared__ int smn[256], smx[256];
    int s = 0x7fffffff, e = -1;
    for (int f = tid; f < 513; f += 256) {
        if (fb[f * 128 + m] != 0.0f) { s = min(s, f); e = max(e, f); }
    }
    smn[tid] = s; smx[tid] = e;
    __syncthreads();
    for (int o = 128; o > 0; o >>= 1) {
        if (tid < o) {
            smn[tid] = min(smn[tid], smn[tid + o]);
            smx[tid] = max(smx[tid], smx[tid + o]);
        }
        __syncthreads();
    }
    int S   = (smx[0] < 0) ? 0 : (smn[0] & ~1);           // force even start
    int cnt = (smx[0] < 0) ? 0 : (smx[0] - S + 1);
    if (cnt > MAXW) cnt = MAXW;
    int cntE = (cnt + 1) & ~1;                             // force even count
    if (tid == 0) { g_fbs[m] = S; g_fbc[m] = cntE; }
    for (int k = tid; k < cntE; k += 256)
        g_fbw[k][m] = (k < cnt) ? fb[(S + k) * 128 + m] : 0.0f;
}

// -------- K1: frames -> windowed rFFT magnitude (f32) -> mel energies E[b][m][t] --------
// R13: cross-lane FFT stages 8/4/2/1 on VALU via DPP; 32/16 via ds_bpermute.
__global__ __launch_bounds__(256)
void pcen_spec_kernel(const float* __restrict__ x, const float* __restrict__ win,
                      float* __restrict__ E)
{
    __shared__ float span[SPAN];        // 19.0 KB
    __shared__ float mags[FPB][MROW];   // 33.3 KB

    const int tid = threadIdx.x;
    const int t0  = blockIdx.x * FPB;
    const int b   = blockIdx.y;

    // ---- load input span with reflect padding ----
    const float* xb = x + (size_t)b * SRLEN;
    for (int j = tid; j < SPAN; j += 256) {
        int src = t0 * 256 + j - 512;
        src = (src < 0) ? -src : src;
        src = (src >= SRLEN) ? (2 * SRLEN - 2 - src) : src;
        span[j] = xb[src];
    }
    __syncthreads();

    const int lane = tid & 63;
    const int wid  = tid >> 6;
    const int lp   = rev6(lane);
    const int p0lane = rev6((64 - lp) & 63);

    // each wave handles 4 frames, fully in registers
    for (int ff = 0; ff < 4; ++ff) {
        const int fr = wid * 4 + ff;
        float zre[8], zim[8];

        // pack: n = rg*64 + lane ; z[n] = xw[2n] + i*xw[2n+1]
        #pragma unroll
        for (int rg = 0; rg < 8; ++rg) {
            int n = rg * 64 + lane;
            float2 sp = *(const float2*)&span[fr * 256 + 2 * n];
            float2 w  = *(const float2*)&win[2 * n];
            zre[rg] = sp.x * w.x;
            zim[rg] = sp.y * w.y;
        }

        // ---- DIF stage m=256: pairs (r, r+4) ----
        #pragma unroll
        for (int rg = 0; rg < 4; ++rg) {
            const float2 tw = g_tw512[rg * 64 + lane];
            float ar = zre[rg], ai = zim[rg], br = zre[rg + 4], bi = zim[rg + 4];
            zre[rg] = ar + br; zim[rg] = ai + bi;
            float dr = ar - br, di = ai - bi;
            zre[rg + 4] = dr * tw.x - di * tw.y;
            zim[rg + 4] = dr * tw.y + di * tw.x;
        }
        // ---- stage m=128: pairs (r, r+2) in each half ----
        #pragma unroll
        for (int h = 0; h < 2; ++h) {
            #pragma unroll
            for (int q = 0; q < 2; ++q) {
                int rt = h * 4 + q, rb = rt + 2;
                const float2 tw = g_tw512[(q * 64 + lane) * 2];
                float ar = zre[rt], ai = zim[rt], br = zre[rb], bi = zim[rb];
                zre[rt] = ar + br; zim[rt] = ai + bi;
                float dr = ar - br, di = ai - bi;
                zre[rb] = dr * tw.x - di * tw.y;
                zim[rb] = dr * tw.y + di * tw.x;
            }
        }
        // ---- stage m=64: pairs (r, r+1) ----
        {
            const float2 tw = g_tw512[lane * 4];
            #pragma unroll
            for (int rt = 0; rt < 8; rt += 2) {
                int rb = rt + 1;
                float ar = zre[rt], ai = zim[rt], br = zre[rb], bi = zim[rb];
                zre[rt] = ar + br; zim[rt] = ai + bi;
                float dr = ar - br, di = ai - bi;
                zre[rb] = dr * tw.x - di * tw.y;
                zim[rb] = dr * tw.y + di * tw.x;
            }
        }

        // ---- 6 cross-lane stages. Partner via DS shuffle (32,16) or DPP (8,4,2,1). ----
        #define BFLY(MASK, PRE, PIM) { \
            const float2 tw = g_tw512[(lane & ((MASK) - 1)) * (256 / (MASK))]; \
            const bool bot = (lane & (MASK)) != 0; \
            const float cw = bot ? tw.x : 1.0f; \
            const float sw = bot ? tw.y : 0.0f; \
            const float sg = bot ? -1.0f : 1.0f; \
            _Pragma("unroll") \
            for (int rg = 0; rg < 8; ++rg) { \
                float orr = zre[rg], oii = zim[rg]; \
                float prr = (PRE); \
                float pri = (PIM); \
                float tr = fmaf(sg, orr, prr); \
                float ti = fmaf(sg, oii, pri); \
                zre[rg] = tr * cw - ti * sw; \
                zim[rg] = tr * sw + ti * cw; \
            } }

        BFLY(32, __shfl_xor(orr, 32), __shfl_xor(oii, 32))
        BFLY(16, __shfl_xor(orr, 16), __shfl_xor(oii, 16))
        BFLY(8,  DPPF(DPPF(orr, 0x140), 0x141), DPPF(DPPF(oii, 0x140), 0x141))  // xor8 = 15^7
        BFLY(4,  DPPF(DPPF(orr, 0x141), 0x1B),  DPPF(DPPF(oii, 0x141), 0x1B))   // xor4 = 7^3
        BFLY(2,  DPPF(orr, 0x4E),               DPPF(oii, 0x4E))                // xor2
        BFLY(1,  DPPF(orr, 0xB1),               DPPF(oii, 0xB1))                // xor1
        #undef BFLY

        // natural Z order: lane lp holds Z[8*lp + q] at reg R3[q]; R3 = {0,4,2,6,1,5,3,7}
        #define WRE(q) zre[(q)==0?0:(q)==1?4:(q)==2?2:(q)==3?6:(q)==4?1:(q)==5?5:(q)==6?3:7]
        #define WIM(q) zim[(q)==0?0:(q)==1?4:(q)==2?2:(q)==3?6:(q)==4?1:(q)==5?5:(q)==6?3:7]

        float mg[8];
        #define MAG(q, MR, MI) { \
            float zr = WRE(q), zi = WIM(q); \
            float mr = (MR), mi = (MI); \
            const float2 tw = g_twu[lp * 8 + (q)]; \
            float xer = 0.5f * (zr + mr), xei = 0.5f * (zi - mi); \
            float xo  = 0.5f * (zi + mi), xoi = 0.5f * (mr - zr); \
            float xr = xer + tw.x * xo - tw.y * xoi; \
            float xi = xei + tw.x * xoi + tw.y * xo; \
            mg[q] = sqrtf(xr * xr + xi * xi); }

        {
            float p0re = __shfl(WRE(0), p0lane);
            float p0im = __shfl(WIM(0), p0lane);
            MAG(0, p0re, p0im)
        }
        {
            float pr = __shfl_xor(WRE(4), 63);
            float pi = __shfl_xor(WIM(4), 63);
            MAG(4, pr, pi)
        }
        #pragma unroll
        for (int q = 1; q <= 3; ++q) {
            float prq  = __shfl_xor(WRE(q), 63);
            float piq  = __shfl_xor(WIM(q), 63);
            float prq8 = __shfl_xor(WRE(8 - q), 63);
            float piq8 = __shfl_xor(WIM(8 - q), 63);
            MAG(q, prq8, piq8)
            MAG(8 - q, prq, piq)
        }
        #undef MAG
        #undef WRE
        #undef WIM

        *(float4*)&mags[fr][lp * 8]     = make_float4(mg[0], mg[1], mg[2], mg[3]);
        *(float4*)&mags[fr][lp * 8 + 4] = make_float4(mg[4], mg[5], mg[6], mg[7]);
        if (lane == 0) {
            mags[fr][512] = fabsf(zre[0] - zim[0]);  // Nyquist
            mags[fr][513] = 0.0f;                    // pad for float2 mel reads
        }
    }
    __syncthreads();

    // ---- sparse mel projection via float2: m = tid&127, fg = tid>>7 covers 8 frames ----
    const int m  = tid & 127;
    const int fg = tid >> 7;
    const int s0 = g_fbs[m];   // even
    const int cn = g_fbc[m];   // even
    float acc[8] = {0, 0, 0, 0, 0, 0, 0, 0};
    for (int k = 0; k < cn; k += 2) {
        const float w0 = g_fbw[k][m];
        const float w1 = g_fbw[k + 1][m];
        const int f = s0 + k;
        #pragma unroll
        for (int j = 0; j < 8; ++j) {
            const float2 v = *(const float2*)&mags[fg * 8 + j][f];
            acc[j] = fmaf(w0, v.x, fmaf(w1, v.y, acc[j]));
        }
    }
    #pragma unroll
    for (int j = 0; j < 8; ++j) {
        int t = t0 + fg * 8 + j;
        if (t < NFRAMES)
            E[((size_t)(b * 128 + m)) * NFRAMES + t] = acc[j];
    }
}

// -------- K2: per-(b,m) IIR scan + PCEN nonlinearity (R1 structure: global access,
//          LDS only for the 256-wide scan; r==0.5 sqrt fast path) --------
__global__ __launch_bounds__(256)
void pcen_scan_kernel(float* __restrict__ E, const float* __restrict__ alpha,
                      const float* __restrict__ delta, const float* __restrict__ rr)
{
    __shared__ float sA[256], sB[256];
    const int tid = threadIdx.x;
    const int bm  = blockIdx.x;
    const int m   = bm & 127;
    const size_t row = (size_t)bm * NFRAMES;

    const float al = alpha[m], de = delta[m], rp = rr[m];
    const bool  half_pow = (rp == 0.5f);
    const float dpr = half_pow ? sqrtf(de) : __powf(de, rp);

    float e[10];
    #pragma unroll
    for (int j = 0; j < 10; ++j) {
        int t = tid * 10 + j;
        e[j] = (t < NFRAMES) ? E[row + t] : 0.0f;
    }

    // local fold of (a,b) pairs; identity (1,0) for padding
    float A = 1.0f, B = 0.0f;
    #pragma unroll
    for (int j = 0; j < 10; ++j) {
        int t = tid * 10 + j;
        bool v = t < NFRAMES;
        float a  = (t == 0) ? 1.0f : (v ? 0.96f : 1.0f);
        float bv = (t == 0) ? e[0] : (v ? 0.04f * e[j] : 0.0f);
        A *= a;
        B = a * B + bv;
    }
    sA[tid] = A; sB[tid] = B;
    __syncthreads();

    // Hillis-Steele inclusive scan over thread chunks
    for (int off = 1; off < 256; off <<= 1) {
        float a2 = sA[tid], b2 = sB[tid];
        float a1 = 1.0f, b1 = 0.0f;
        if (tid >= off) { a1 = sA[tid - off]; b1 = sB[tid - off]; }
        __syncthreads();
        sA[tid] = a1 * a2;
        sB[tid] = a2 * b1 + b2;
        __syncthreads();
    }
    float M = (tid > 0) ? sB[tid - 1] : 0.0f;   // carry: M before this chunk

    #pragma unroll
    for (int j = 0; j < 10; ++j) {
        int t = tid * 10 + j;
        bool v = t < NFRAMES;
        float a  = (t == 0) ? 1.0f : (v ? 0.96f : 1.0f);
        float bv = (t == 0) ? e[0] : (v ? 0.04f * e[j] : 0.0f);
        M = a * M + bv;
        if (v) {
            float inv = __powf(M + 1e-6f, -al);            // smooth^-1
            float val = fmaf(e[j], inv, de);
            float pw  = half_pow ? sqrtf(val) : __powf(val, rp);
            E[row + t] = pw - dpr;
        }
    }
}

extern "C" void kernel_launch(void* const* d_in, const int* in_sizes, int n_in,
                              void* d_out, int out_size, void* d_ws, size_t ws_size,
                              hipStream_t stream)
{
    const float* x     = (const float*)d_in[0];
    const float* alpha = (const float*)d_in[1];
    const float* delta = (const float*)d_in[2];
    const float* r     = (const float*)d_in[3];
    const float* fb    = (const float*)d_in[4];
    const float* win   = (const float*)d_in[5];
    float* out = (float*)d_out;

    pcen_setup_kernel<<<128, 256, 0, stream>>>(fb);
    dim3 g1((NFRAMES + FPB - 1) / FPB, 32);   // 157 x 32
    pcen_spec_kernel<<<g1, 256, 0, stream>>>(x, win, out);
    pcen_scan_kernel<<<32 * 128, 256, 0, stream>>>(out, alpha, delta, r);
}